// Round 2
// baseline (128.602 us; speedup 1.0000x reference)
//
#include <hip/hip_runtime.h>
#include <hip/hip_cooperative_groups.h>

namespace cg = cooperative_groups;

#define NUM_PAGES 1048576
#define TPP 32
#define SLOTS 256
#define MPPS 4096
#define NBLK 256
#define NTHR 1024
// Each block owns a chunk of NUM_PAGES/NBLK = 4096 ints = 1024 int4 (1 int4/thread).

__global__ __launch_bounds__(NTHR) void fused_kernel(
    const int* __restrict__ ps, const int* __restrict__ pm,
    const int* __restrict__ seq, const int* __restrict__ npu,
    const int* __restrict__ cp, int* __restrict__ out, int* __restrict__ ws)
{
    const int t    = threadIdx.x;
    const int b    = blockIdx.x;
    const int lane = t & 63;
    const int wave = t >> 6;
    const unsigned long long mask_lt = (1ULL << lane) - 1ULL;

    int* out_ps  = out;                     // NUM_PAGES
    int* out_pm  = out + NUM_PAGES;         // SLOTS*MPPS == NUM_PAGES
    int* out_seq = out + 2 * NUM_PAGES;     // SLOTS each below
    int* out_npu = out_seq + SLOTS;
    int* out_cp  = out_npu + SLOTS;
    int* out_cpp = out_cp + SLOTS;

    __shared__ int s_need_slot[SLOTS];  // compacted needing slots
    __shared__ int s_fixcol[SLOTS];     // npu[slot] for each needing slot
    __shared__ int s_free[SLOTS];       // ascending free-page indices
    __shared__ int s_scan[16];          // per-wave scratch (phase A count + phase B)
    __shared__ int s_scan2[16];         // block-0 needs compaction scratch
    __shared__ int s_cnt[NBLK];         // per-chunk free counts
    __shared__ int s_pre[NBLK];         // exclusive prefix of counts
    __shared__ int s_K, s_cursor;

    // ---- Phase A: copy (int4) + count frees in my chunk --------------------
    const int gi = b * NTHR + t;  // int4 index; NBLK*NTHR == NUM_PAGES/4 exactly
    const int4 v = reinterpret_cast<const int4*>(ps)[gi];
    reinterpret_cast<int4*>(out_ps)[gi] = v;
    reinterpret_cast<int4*>(out_pm)[gi] = reinterpret_cast<const int4*>(pm)[gi];

    int nf = (v.x == 0) + (v.y == 0) + (v.z == 0) + (v.w == 0);
    if (gi == 0 && v.x == 0) nf--;      // index 0 is never allocatable
    for (int o = 32; o; o >>= 1) nf += __shfl_down(nf, o);
    if (lane == 0) s_scan[wave] = nf;
    __syncthreads();
    if (t == 0) {
        int a = 0;
        for (int w = 0; w < 16; ++w) a += s_scan[w];
        ws[b] = a;
    }

    // block 0 also does the per-slot math + needs compaction (overlapped)
    int needs = 0, mynpu = 0;
    if (b == 0) {
        if (t < SLOTS) {
            int s = seq[t], c = cp[t];
            mynpu = npu[t];
            int ns = s + ((c == -1) ? 0 : 1);
            int nn = (ns + TPP - 1) / TPP;
            out_seq[t] = ns;
            out_npu[t] = nn;
            out_cpp[t] = (ns == 0) ? 0 : ((ns - 1) % TPP);
            out_cp[t]  = c;             // provisional; fixed in phase B
            needs = (nn > mynpu) ? 1 : 0;
        }
        unsigned long long bal = __ballot(needs);
        int rank = __popcll(bal & mask_lt);
        if (lane == 0) s_scan2[wave] = __popcll(bal);
        __syncthreads();
        if (t == 0) {
            int a = 0;
            for (int w = 0; w < 16; ++w) { int q = s_scan2[w]; s_scan2[w] = a; a += q; }
            s_K = a;
            s_cursor = 0;
        }
        __syncthreads();
        if (needs) {
            int p = s_scan2[wave] + rank;
            s_need_slot[p] = t;
            s_fixcol[p]    = mynpu;
        }
    }

    __threadfence();
    cg::this_grid().sync();
    if (b != 0) return;

    // ---- Phase B (block 0 only) --------------------------------------------
    const int K = s_K;

    // exclusive prefix over the 256 chunk counts (waves 0-3 active-useful)
    int cc = (t < NBLK) ? ws[t] : 0;
    int x = cc;
    for (int o = 1; o < 64; o <<= 1) { int y = __shfl_up(x, o); if (lane >= o) x += y; }
    if (lane == 63) s_scan[wave] = x;
    __syncthreads();
    if (t == 0) {
        int a = 0;
        for (int w = 0; w < 16; ++w) { int q = s_scan[w]; s_scan[w] = a; a += q; }
    }
    __syncthreads();
    if (t < NBLK) { s_pre[t] = x - cc + s_scan[wave]; s_cnt[t] = cc; }
    __syncthreads();

    // rescan only chunks holding the first K frees (L2/L3-hot)
    for (int c = 0; c < NBLK && s_cursor < K; ++c) {
        if (s_cnt[c] == 0 || s_pre[c] >= K) continue;
        for (int sub = 0; sub < 4; ++sub) {
            int idx = c * 4096 + sub * NTHR + t;
            int isfree = (idx > 0 && ps[idx] == 0) ? 1 : 0;
            unsigned long long fb = __ballot(isfree);
            int frank = __popcll(fb & mask_lt);
            if (lane == 0) s_scan[wave] = __popcll(fb);
            __syncthreads();
            if (t == 0) {
                int a = s_cursor;
                for (int w = 0; w < 16; ++w) { int q = s_scan[w]; s_scan[w] = a; a += q; }
                s_cursor = a;
            }
            __syncthreads();
            if (isfree) {
                int pos = s_scan[wave] + frank;
                if (pos < K) s_free[pos] = idx;
            }
            __syncthreads();
        }
    }

    // fallback: not enough free pages -> reference yields index 0
    if (t < K && t >= s_cursor) s_free[t] = 0;
    __syncthreads();

    // apply the K allocations
    if (t < K) {
        int slot = s_need_slot[t];
        int nfp  = s_free[t];
        out_ps[nfp] = 1;
        out_pm[slot * MPPS + s_fixcol[t]] = nfp;
        out_cp[slot] = nfp;
    }
}

// ---------------------------------------------------------------------------
extern "C" void kernel_launch(void* const* d_in, const int* in_sizes, int n_in,
                              void* d_out, int out_size, void* d_ws, size_t ws_size,
                              hipStream_t stream)
{
    const int* page_status = (const int*)d_in[0];
    const int* page_map    = (const int*)d_in[1];
    const int* seq         = (const int*)d_in[2];
    const int* npu         = (const int*)d_in[3];
    const int* cp          = (const int*)d_in[4];
    // d_in[5] (current_page_position) is unused by the reference update.

    int* out = (int*)d_out;
    int* ws  = (int*)d_ws;   // needs NBLK ints

    void* args[] = {
        (void*)&page_status, (void*)&page_map, (void*)&seq,
        (void*)&npu, (void*)&cp, (void*)&out, (void*)&ws
    };
    hipLaunchCooperativeKernel((const void*)fused_kernel,
                               dim3(NBLK), dim3(NTHR), args, 0, stream);
}

// Round 3
// 101.735 us; speedup vs baseline: 1.2641x; 1.2641x over previous
//
#include <hip/hip_runtime.h>

#define NUM_PAGES 1048576
#define TPP 32
#define SLOTS 256
#define MPPS 4096
#define NBLK 1024
#define NTHR 256
#define CHUNK 1024            // ints of page_status per block

// ws layout (ints)
#define WS_CTR   0            // arrival counter (memset to 0 each launch)
#define WS_K     1            // number of slots needing a page
#define WS_NEED  8            // [8, 8+SLOTS): compacted needing-slot ids
#define WS_COL   (8 + SLOTS)  // [.., +SLOTS): npu[slot] (pm column to write)
#define WS_CNT   1024         // [1024, 2048): per-chunk free-page counts

__global__ __launch_bounds__(NTHR) void fused_kernel(
    const int* __restrict__ ps, const int* __restrict__ pm,
    const int* __restrict__ seq, const int* __restrict__ npu,
    const int* __restrict__ cp, int* __restrict__ out, int* __restrict__ ws)
{
    const int t    = threadIdx.x;
    const int b    = blockIdx.x;
    const int lane = t & 63;
    const int wave = t >> 6;
    const unsigned long long mlt = (1ULL << lane) - 1ULL;

    int* out_ps  = out;                     // NUM_PAGES
    int* out_pm  = out + NUM_PAGES;         // SLOTS*MPPS == NUM_PAGES
    int* out_seq = out + 2 * NUM_PAGES;
    int* out_npu = out_seq + SLOTS;
    int* out_cp  = out_npu + SLOTS;
    int* out_cpp = out_cp + SLOTS;

    __shared__ int s_w[4];
    __shared__ int s_tail;
    __shared__ int s_cnt[NBLK];     // tail: chunk free counts
    __shared__ int s_selc[SLOTS];   // tail: selected chunk ids
    __shared__ int s_selbase[SLOTS];// tail: free-rank base of each selected chunk
    __shared__ int s_free[SLOTS];   // tail: ascending free page indices
    __shared__ int s_nsel, s_found;

    // ---- Phase A: copy int4 chunk + count free pages -----------------------
    const int gi = b * NTHR + t;    // int4 index; NBLK*NTHR == NUM_PAGES/4
    const int4 v = reinterpret_cast<const int4*>(ps)[gi];
    reinterpret_cast<int4*>(out_ps)[gi] = v;
    reinterpret_cast<int4*>(out_pm)[gi] = reinterpret_cast<const int4*>(pm)[gi];

    int nf = (v.x == 0) + (v.y == 0) + (v.z == 0) + (v.w == 0);
    if (gi == 0 && v.x == 0) nf--;          // page index 0 never allocatable
    for (int o = 32; o; o >>= 1) nf += __shfl_down(nf, o);
    if (lane == 0) s_w[wave] = nf;
    __syncthreads();
    if (t == 0) ws[WS_CNT + b] = s_w[0] + s_w[1] + s_w[2] + s_w[3];

    // ---- Block 0: slot math + needs compaction (overlaps other copies) -----
    if (b == 0) {
        int s = seq[t], c = cp[t], u = npu[t];
        int ns = s + ((c == -1) ? 0 : 1);
        int nn = (ns + TPP - 1) / TPP;
        out_seq[t] = ns;
        out_npu[t] = nn;
        out_cpp[t] = (ns == 0) ? 0 : ((ns - 1) % TPP);
        out_cp[t]  = c;                     // provisional; tail fixes allocated slots
        int needs = (nn > u) ? 1 : 0;
        unsigned long long bal = __ballot(needs);
        int rank = __popcll(bal & mlt);
        __syncthreads();                    // s_w reuse
        if (lane == 0) s_w[wave] = __popcll(bal);
        __syncthreads();
        int woff = 0;
        for (int w = 0; w < wave; ++w) woff += s_w[w];
        if (needs) { int p = woff + rank; ws[WS_NEED + p] = t; ws[WS_COL + p] = u; }
        if (t == 0) ws[WS_K] = s_w[0] + s_w[1] + s_w[2] + s_w[3];
    }

    // ---- Arrival: last block runs the tail ---------------------------------
    __threadfence();
    __syncthreads();
    if (t == 0) {
        int old = atomicAdd(&ws[WS_CTR], 1);
        s_tail = (old == NBLK - 1) ? 1 : 0;
    }
    __syncthreads();
    if (!s_tail) return;
    __threadfence();                        // acquire: see all blocks' writes

    // ---- Tail: find first K free pages, apply fix-ups ----------------------
    const int K = ws[WS_K];
    for (int j = t; j < NBLK; j += NTHR) s_cnt[j] = ws[WS_CNT + j];
    __syncthreads();
    if (t == 0) {
        int acc = 0, n = 0;
        for (int c = 0; c < NBLK && acc < K; ++c) {
            int q = s_cnt[c];
            if (q > 0) { s_selc[n] = c; s_selbase[n] = acc; ++n; acc += q; }
        }
        s_nsel = n;
        s_found = (acc < K) ? acc : K;
    }
    __syncthreads();
    const int nsel = s_nsel;

    for (int si = 0; si < nsel; ++si) {
        int c = s_selc[si], base = s_selbase[si];
        int i0 = c * CHUNK + t * 4;         // 256 threads x 4 ints = 1024-int chunk
        int m = 0;
        #pragma unroll
        for (int j = 0; j < 4; ++j) {
            int idx = i0 + j;
            if (idx > 0 && ps[idx] == 0) m |= 1 << j;
        }
        int q = __popc(m);
        int x = q;                          // inclusive wave scan
        for (int o = 1; o < 64; o <<= 1) { int y = __shfl_up(x, o); if (lane >= o) x += y; }
        if (lane == 63) s_w[wave] = x;
        __syncthreads();
        int woff = 0;
        for (int w = 0; w < wave; ++w) woff += s_w[w];
        int pos = base + woff + x - q;      // exclusive rank of my first free
        #pragma unroll
        for (int j = 0; j < 4; ++j) {
            if (m & (1 << j)) {
                int p = pos + __popc(m & ((1 << j) - 1));
                if (p < K) s_free[p] = i0 + j;
            }
        }
        __syncthreads();
    }
    if (t < K && t >= s_found) s_free[t] = 0;   // no free page -> index 0
    __syncthreads();

    if (t < K) {
        int slot = ws[WS_NEED + t];
        int col  = ws[WS_COL + t];
        int nfp  = s_free[t];
        out_ps[nfp] = 1;
        out_pm[slot * MPPS + col] = nfp;
        out_cp[slot] = nfp;
    }
}

// ---------------------------------------------------------------------------
extern "C" void kernel_launch(void* const* d_in, const int* in_sizes, int n_in,
                              void* d_out, int out_size, void* d_ws, size_t ws_size,
                              hipStream_t stream)
{
    const int* page_status = (const int*)d_in[0];
    const int* page_map    = (const int*)d_in[1];
    const int* seq         = (const int*)d_in[2];
    const int* npu         = (const int*)d_in[3];
    const int* cp          = (const int*)d_in[4];
    // d_in[5] (current_page_position) unused by the reference update.

    int* out = (int*)d_out;
    int* ws  = (int*)d_ws;    // uses 2048 ints = 8 KB

    hipMemsetAsync(ws + WS_CTR, 0, sizeof(int), stream);   // arrival counter = 0

    fused_kernel<<<NBLK, NTHR, 0, stream>>>(
        page_status, page_map, seq, npu, cp, out, ws);
}

// Round 4
// 10.557 us; speedup vs baseline: 12.1812x; 9.6364x over previous
//
#include <hip/hip_runtime.h>

#define NUM_PAGES 1048576
#define TPP 32
#define SLOTS 256
#define MPPS 4096
#define NBLK 1024
#define NTHR 256
// each block owns NUM_PAGES/NBLK = 1024 ints (256 int4) of ps and of pm

__global__ __launch_bounds__(NTHR) void fused(
    const int* __restrict__ ps, const int* __restrict__ pm,
    const int* __restrict__ seq, const int* __restrict__ npu,
    const int* __restrict__ cp, int* __restrict__ out)
{
    const int t = threadIdx.x, b = blockIdx.x;
    const int lane = t & 63, wave = t >> 6;
    const unsigned long long mlt = (1ULL << lane) - 1ULL;

    int* out_ps  = out;                     // NUM_PAGES
    int* out_pm  = out + NUM_PAGES;         // SLOTS*MPPS == NUM_PAGES
    int* out_seq = out + 2 * NUM_PAGES;
    int* out_npu = out_seq + SLOTS;
    int* out_cp  = out_npu + SLOTS;
    int* out_cpp = out_cp + SLOTS;

    __shared__ int s_w[4];
    __shared__ int s_free[SLOTS];
    __shared__ int s_found;

    // ---- issue own-chunk copy loads first (latency hides under logic) ------
    const int gi = b * NTHR + t;            // int4 index
    const int4 pv = reinterpret_cast<const int4*>(ps)[gi];
    const int4 mv = reinterpret_cast<const int4*>(pm)[gi];

    // ---- phase 1: slot math, every block (t == slot id) --------------------
    int sq = seq[t], c = cp[t], u = npu[t];
    int ns = sq + (c != -1);
    int nn = (ns + TPP - 1) / TPP;
    int ncpp = (ns == 0) ? 0 : ((ns - 1) & (TPP - 1));
    int needs = (nn > u) ? 1 : 0;
    unsigned long long bal = __ballot(needs);
    if (lane == 0) s_w[wave] = __popcll(bal);
    if (t == 0) s_found = 0;
    __syncthreads();
    int woff = 0;
    for (int w = 0; w < wave; ++w) woff += s_w[w];
    const int r = woff + __popcll(bal & mlt);          // my slot's alloc rank
    const int K = s_w[0] + s_w[1] + s_w[2] + s_w[3];   // slots needing a page
    __syncthreads();                                   // s_w reused below

    // ---- phase 2: every block finds the first K free pages (ascending) ----
    for (int base = 0; base < NUM_PAGES && s_found < K; base += 4 * NTHR) {
        int4 v = reinterpret_cast<const int4*>(ps)[(base >> 2) + t];
        int m = ((v.x == 0) ? 1 : 0) | ((v.y == 0) ? 2 : 0) |
                ((v.z == 0) ? 4 : 0) | ((v.w == 0) ? 8 : 0);
        if (base == 0 && t == 0) m &= ~1;              // page 0 never allocatable
        int q = __popc(m);
        int x = q;                                     // inclusive wave scan
        for (int o = 1; o < 64; o <<= 1) { int y = __shfl_up(x, o); if (lane >= o) x += y; }
        if (lane == 63) s_w[wave] = x;
        __syncthreads();
        int wo = 0;
        for (int w = 0; w < wave; ++w) wo += s_w[w];
        int pos = s_found + wo + x - q;                // excl. global rank of my 1st free
        #pragma unroll
        for (int j = 0; j < 4; ++j) if (m & (1 << j)) {
            int p = pos + __popc(m & ((1 << j) - 1));
            if (p < K) s_free[p] = base + t * 4 + j;
        }
        __syncthreads();
        if (t == 0) s_found += s_w[0] + s_w[1] + s_w[2] + s_w[3];
        __syncthreads();
    }
    const int fe = (s_found < K) ? s_found : K;        // frees actually found

    // ---- phase 3: copy own chunks ------------------------------------------
    reinterpret_cast<int4*>(out_ps)[gi] = pv;
    reinterpret_cast<int4*>(out_pm)[gi] = mv;
    __syncthreads();                                   // copy before own patches

    // ---- phase 4: patches, strictly by chunk owner -------------------------
    const int nfp = (needs && r < fe) ? s_free[r] : 0; // my slot's page (0 = none)
    if (b == 0) {                                      // slot vectors: block 0 only
        out_seq[t] = ns;
        out_npu[t] = nn;
        out_cpp[t] = ncpp;
        out_cp[t]  = needs ? nfp : c;
    }
    // pm patch: done by the block that copied that pm chunk (chunk = 4*slot + u/1024)
    if (needs && t == (b >> 2) && (u >> 10) == (b & 3))
        out_pm[t * MPPS + u] = nfp;
    // ps patch: done by the block that copied that ps chunk (chunk = page/1024)
    if (t < K) {
        int f = (t < fe) ? s_free[t] : 0;
        if ((f >> 10) == b) out_ps[f] = 1;
    }
}

// ---------------------------------------------------------------------------
extern "C" void kernel_launch(void* const* d_in, const int* in_sizes, int n_in,
                              void* d_out, int out_size, void* d_ws, size_t ws_size,
                              hipStream_t stream)
{
    const int* page_status = (const int*)d_in[0];
    const int* page_map    = (const int*)d_in[1];
    const int* seq         = (const int*)d_in[2];
    const int* npu         = (const int*)d_in[3];
    const int* cp          = (const int*)d_in[4];
    // d_in[5] (current_page_position) unused by the reference update.

    fused<<<NBLK, NTHR, 0, stream>>>(
        page_status, page_map, seq, npu, cp, (int*)d_out);
}

// Round 5
// 10.501 us; speedup vs baseline: 12.2471x; 1.0054x over previous
//
#include <hip/hip_runtime.h>

#define NUM_PAGES 1048576
#define TPP 32
#define SLOTS 256
#define MPPS 4096
#define NBLK 1024
#define NTHR 256
// each block owns NUM_PAGES/NBLK = 1024 ints (256 int4) of ps and of pm

__global__ __launch_bounds__(NTHR) void fused(
    const int* __restrict__ ps, const int* __restrict__ pm,
    const int* __restrict__ seq, const int* __restrict__ npu,
    const int* __restrict__ cp, int* __restrict__ out)
{
    const int t = threadIdx.x, b = blockIdx.x;
    const int lane = t & 63, wave = t >> 6;
    const unsigned long long mlt = (1ULL << lane) - 1ULL;

    int* out_ps  = out;                     // NUM_PAGES
    int* out_pm  = out + NUM_PAGES;         // SLOTS*MPPS == NUM_PAGES
    int* out_seq = out + 2 * NUM_PAGES;
    int* out_npu = out_seq + SLOTS;
    int* out_cp  = out_npu + SLOTS;
    int* out_cpp = out_cp + SLOTS;

    __shared__ int s_w[4];
    __shared__ int s_free[SLOTS];
    __shared__ int s_found;

    const int4* ps4 = reinterpret_cast<const int4*>(ps);

    // ---- issue ALL loads up front ------------------------------------------
    const int gi = b * NTHR + t;            // int4 index of my copy element
    const int4 pv = ps4[gi];
    const int4 mv = reinterpret_cast<const int4*>(pm)[gi];
    const int4 pc0 = ps4[t];                // scan-chunk prefetch (pages 0..1023)
    const int4 pc1 = ps4[NTHR + t];         // pages 1024..2047
    const int4 pc2 = ps4[2 * NTHR + t];     // pages 2048..3071
    const int sq = seq[t], c = cp[t], u = npu[t];

    // ---- copy stores ASAP: stream under the logic --------------------------
    reinterpret_cast<int4*>(out_ps)[gi] = pv;
    reinterpret_cast<int4*>(out_pm)[gi] = mv;

    // ---- phase 1: slot math (t == slot id), every block --------------------
    int ns = sq + (c != -1);
    int nn = (ns + TPP - 1) / TPP;
    int ncpp = (ns == 0) ? 0 : ((ns - 1) & (TPP - 1));
    int needs = (nn > u) ? 1 : 0;
    unsigned long long bal = __ballot(needs);
    if (lane == 0) s_w[wave] = __popcll(bal);
    if (t == 0) s_found = 0;
    __syncthreads();                        // also drains copy stores (vmcnt)
    int woff = 0;
    for (int w = 0; w < wave; ++w) woff += s_w[w];
    const int r = woff + __popcll(bal & mlt);          // my slot's alloc rank
    const int K = s_w[0] + s_w[1] + s_w[2] + s_w[3];   // slots needing a page
    if (b == 0) {                                      // early slot-vector stores
        out_seq[t] = ns;
        out_npu[t] = nn;
        out_cpp[t] = ncpp;
    }
    __syncthreads();                        // s_w reused below

    // ---- phase 2: find first K free pages (ascending), 2 barriers/chunk ----
    auto process = [&](int4 v, int ch) {
        int m = ((v.x == 0) ? 1 : 0) | ((v.y == 0) ? 2 : 0) |
                ((v.z == 0) ? 4 : 0) | ((v.w == 0) ? 8 : 0);
        if (ch == 0 && t == 0) m &= ~1;     // page 0 never allocatable
        int q = __popc(m);
        int x = q;                          // inclusive wave scan
        for (int o = 1; o < 64; o <<= 1) { int y = __shfl_up(x, o); if (lane >= o) x += y; }
        if (lane == 63) s_w[wave] = x;
        int sf = s_found;                   // stable since last barrier
        __syncthreads();
        int wo = 0;
        for (int w = 0; w < wave; ++w) wo += s_w[w];
        int pos = sf + wo + x - q;          // excl. global rank of my 1st free
        #pragma unroll
        for (int j = 0; j < 4; ++j) if (m & (1 << j)) {
            int p = pos + __popc(m & ((1 << j) - 1));
            if (p < K) s_free[p] = ch * 1024 + t * 4 + j;
        }
        if (t == 0) s_found = sf + s_w[0] + s_w[1] + s_w[2] + s_w[3];
        __syncthreads();
    };

    process(pc0, 0);
    if (s_found < K) process(pc1, 1);
    if (s_found < K) process(pc2, 2);
    for (int ch = 3; ch < NBLK && s_found < K; ++ch)
        process(ps4[ch * NTHR + t], ch);    // cold-path correctness fallback

    const int fe = (s_found < K) ? s_found : K;        // frees actually found

    // ---- phase 3: patches, strictly by chunk owner -------------------------
    const int nfp = (needs && r < fe) ? s_free[r] : 0; // my slot's page (0 = none)
    if (b == 0) out_cp[t] = needs ? nfp : c;
    // pm patch: by the block owning that pm chunk (chunk = 4*slot + u/1024)
    if (needs && t == (b >> 2) && (u >> 10) == (b & 3))
        out_pm[t * MPPS + u] = nfp;
    // ps patch: by the block owning that ps chunk (chunk = page/1024)
    if (t < K) {
        int f = (t < fe) ? s_free[t] : 0;
        if ((f >> 10) == b) out_ps[f] = 1;
    }
}

// ---------------------------------------------------------------------------
extern "C" void kernel_launch(void* const* d_in, const int* in_sizes, int n_in,
                              void* d_out, int out_size, void* d_ws, size_t ws_size,
                              hipStream_t stream)
{
    const int* page_status = (const int*)d_in[0];
    const int* page_map    = (const int*)d_in[1];
    const int* seq         = (const int*)d_in[2];
    const int* npu         = (const int*)d_in[3];
    const int* cp          = (const int*)d_in[4];
    // d_in[5] (current_page_position) unused by the reference update.

    fused<<<NBLK, NTHR, 0, stream>>>(
        page_status, page_map, seq, npu, cp, (int*)d_out);
}